// Round 3
// baseline (803.945 us; speedup 1.0000x reference)
//
#include <hip/hip_runtime.h>
#include <math.h>

#define HH 256
#define WW 256
#define HW (HH * WW)
#define TB 10

__device__ __forceinline__ float sp10(float x) {
    float z = 10.0f * x;
    return (fmaxf(z, 0.0f) + log1pf(expf(-fabsf(z)))) * 0.1f;
}

// ---------------------------------------------------------------------------
// Weight transpose: OIHW -> [ci][tap][co] (co contiguous) for scalar-load use.
// wt3 picks only the 54 needed channels: [ci][tap][(tt-1)*6+g].
// ---------------------------------------------------------------------------
__global__ __launch_bounds__(256) void transpose_weights(
    const float* __restrict__ w1, const float* __restrict__ w2,
    const float* __restrict__ w3,
    float* __restrict__ wt1, float* __restrict__ wt2, float* __restrict__ wt3)
{
    int idx = blockIdx.x * 256 + threadIdx.x;
    if (idx < 2880) {               // conv1: (32,10,3,3) -> [ci<10][tap<9][co<32]
        int ci = idx / 288; int rem = idx - ci * 288;
        int tap = rem / 32; int co = rem - tap * 32;
        wt1[idx] = w1[co * 90 + ci * 9 + tap];
    }
    if (idx < 18432) {              // conv2: (64,32,3,3) -> [ci<32][tap<9][co<64]
        int ci = idx / 576; int rem = idx - ci * 576;
        int tap = rem / 64; int co = rem - tap * 64;
        wt2[idx] = w2[co * 288 + ci * 9 + tap];
    }
    if (idx < 31104) {              // conv3: (60,64,3,3) -> [ci<64][tap<9][54]
        int ci = idx / 486; int rem = idx - ci * 486;
        int tap = rem / 54; int j54 = rem - tap * 54;
        int tt = j54 / 6 + 1;
        int g  = j54 - (tt - 1) * 6;
        wt3[idx] = w3[(g * 10 + tt) * 576 + ci * 9 + tap];
    }
}

// ---------------------------------------------------------------------------
// 2-pixel-per-thread direct 3x3 conv. Block = 256 thr covers 16w x 32h tile
// (vertical pixel pairs). Output channels split into halves via blockIdx.z
// so each scalar weight load feeds 2 FMAs (weight B/FMA-cycle: 2.0 -> 1.0).
// LDS: [CHUNK][34][18] floats.
// ---------------------------------------------------------------------------
template <int CIN, int CHUNK, int COUT, int CO_PER, bool RELU_IN>
__global__ __launch_bounds__(256, 4) void conv2px_k(
    const float* __restrict__ in, const float* __restrict__ wt,
    float* __restrict__ out, int nb)
{
    __shared__ float tile[CHUNK * 612];   // 34*18 = 612 per ci
    const int tx = threadIdx.x & 15, ty = threadIdx.x >> 4;
    const int h0 = blockIdx.y * 32, w0 = blockIdx.x * 16;
    const int z = blockIdx.z;
    const int bz = z % nb, half = z / nb;
    const int base = half * CO_PER;
    const float* inb = in + (size_t)bz * CIN * HW;

    float acc0[CO_PER], acc1[CO_PER];
#pragma unroll
    for (int c = 0; c < CO_PER; ++c) { acc0[c] = 0.0f; acc1[c] = 0.0f; }

    for (int c0 = 0; c0 < CIN; c0 += CHUNK) {
        if (c0) __syncthreads();
        const float* inc = inb + (size_t)c0 * HW;
        for (int i = threadIdx.x; i < CHUNK * 612; i += 256) {
            int ci = i / 612; int r = i - ci * 612;
            int row = r / 18; int col = r - row * 18;
            int gy = h0 + row - 1, gx = w0 + col - 1;
            float v = 0.0f;
            if (gy >= 0 && gy < HH && gx >= 0 && gx < WW)
                v = inc[(size_t)ci * HW + gy * WW + gx];
            if (RELU_IN) v = fmaxf(v, 0.0f);
            tile[i] = v;
        }
        __syncthreads();

        for (int ci = 0; ci < CHUNK; ++ci) {
            const float* tp = &tile[ci * 612 + (2 * ty) * 18 + tx];
            float v[12];
#pragma unroll
            for (int r = 0; r < 4; ++r)
#pragma unroll
                for (int c = 0; c < 3; ++c)
                    v[r * 3 + c] = tp[r * 18 + c];
            const float* wp = wt + (size_t)(c0 + ci) * 9 * COUT + base;
#pragma unroll
            for (int t = 0; t < 9; ++t) {
                float a0 = v[t], a1 = v[t + 3];
#pragma unroll
                for (int c = 0; c < CO_PER; ++c) {
                    float wv = wp[t * COUT + c];
                    acc0[c] = fmaf(wv, a0, acc0[c]);
                    acc1[c] = fmaf(wv, a1, acc1[c]);
                }
            }
        }
    }

    const int h = h0 + 2 * ty, w = w0 + tx;
    float* ob = out + (size_t)bz * COUT * HW + (size_t)base * HW
                    + (size_t)h * WW + w;
#pragma unroll
    for (int c = 0; c < CO_PER; ++c) {
        ob[(size_t)c * HW]      = acc0[c];
        ob[(size_t)c * HW + WW] = acc1[c];
    }
}

// ---------------------------------------------------------------------------
// conv3 (64 -> 54 ch) + epilogue, 2px/thread, channel-halved:
// half 0: acc = global ch 0..29  -> epilogue j = 0..4
// half 1: acc = global ch 24..53 -> epilogue j = 4..8 (+ zero ch 9)
// j = 4 is written identically by both halves (same weights, same order).
// ---------------------------------------------------------------------------
__global__ __launch_bounds__(256, 4) void conv3_final2_k(
    const float* __restrict__ p2, const float* __restrict__ wt3,
    const float* __restrict__ x, const float* __restrict__ pacw,
    const float* __restrict__ pacb, float* __restrict__ out, int nb)
{
    __shared__ float tile[16 * 612];
    const int tx = threadIdx.x & 15, ty = threadIdx.x >> 4;
    const int h0 = blockIdx.y * 32, w0 = blockIdx.x * 16;
    const int z = blockIdx.z;
    const int bz = z % nb, half = z / nb;
    const int base = half * 24;
    const float* pbase = p2 + (size_t)bz * 64 * HW;

    float acc0[30], acc1[30];
#pragma unroll
    for (int c = 0; c < 30; ++c) { acc0[c] = 0.0f; acc1[c] = 0.0f; }

    for (int c0 = 0; c0 < 64; c0 += 16) {
        if (c0) __syncthreads();
        const float* inc = pbase + (size_t)c0 * HW;
        for (int i = threadIdx.x; i < 16 * 612; i += 256) {
            int ci = i / 612; int r = i - ci * 612;
            int row = r / 18; int col = r - row * 18;
            int gy = h0 + row - 1, gx = w0 + col - 1;
            float v = 0.0f;
            if (gy >= 0 && gy < HH && gx >= 0 && gx < WW)
                v = inc[(size_t)ci * HW + gy * WW + gx];
            tile[i] = v;
        }
        __syncthreads();

        for (int ci = 0; ci < 16; ++ci) {
            const float* tp = &tile[ci * 612 + (2 * ty) * 18 + tx];
            float v[12];
#pragma unroll
            for (int r = 0; r < 4; ++r)
#pragma unroll
                for (int c = 0; c < 3; ++c)
                    v[r * 3 + c] = tp[r * 18 + c];
            const float* wp = wt3 + (size_t)(c0 + ci) * 486 + base;
#pragma unroll
            for (int t = 0; t < 9; ++t) {
                float a0 = v[t], a1 = v[t + 3];
#pragma unroll
                for (int c = 0; c < 30; ++c) {
                    float wv = wp[t * 54 + c];
                    acc0[c] = fmaf(wv, a0, acc0[c]);
                    acc1[c] = fmaf(wv, a1, acc1[c]);
                }
            }
        }
    }

    // ---- epilogue ----
    float pw[9];
#pragma unroll
    for (int k = 0; k < 9; ++k) pw[k] = pacw[k];
    const float pbias = pacb[0];
    const int h = h0 + 2 * ty, w = w0 + tx;
    const float* xb = x + (size_t)bz * TB * HW;
    float* ob = out + (size_t)bz * TB * HW;

#pragma unroll
    for (int k = 0; k < 5; ++k) {
        const int j = half * 4 + k;
        const int tt = j + 1;
        const float* xc = xb + (size_t)tt * HW;
        float xv[12];
#pragma unroll
        for (int r = 0; r < 4; ++r)
#pragma unroll
            for (int c = 0; c < 3; ++c) {
                int gy = h + r - 1, gx = w + c - 1;
                xv[r * 3 + c] = (gy >= 0 && gy < HH && gx >= 0 && gx < WW)
                                    ? xc[gy * WW + gx] : 0.0f;
            }
#pragma unroll
        for (int p = 0; p < 2; ++p) {
            const float* ac = p ? acc1 : acc0;
            float kappa = sp10(ac[k * 6 + 0]);
            float m1d   = ac[k * 6 + 1];
            float m2d   = ac[k * 6 + 2];
            float gamma = sp10(ac[k * 6 + 3]);
            float vx    = ac[k * 6 + 4];
            float vy    = ac[k * 6 + 5];
            float H11 = gamma + vx * vx;
            float H22 = gamma + vy * vy;
            float H12 = vx * vy;
            float iH11 = 1.0f / H11;
            float iH22 = 1.0f / H22;
            float wk[9];
            wk[0] = -0.5f * H12;  wk[1] = -iH22 + m1d;  wk[2] = 0.5f * H12;
            wk[3] = -iH11 - m2d;
            wk[4] = kappa + 2.0f * H11 + 2.0f * H22 + 1.0f;
            wk[5] = -iH11 + m2d;
            wk[6] = 0.5f * H12;   wk[7] = -iH22 - m1d;  wk[8] = -0.5f * H12;
            float s = 0.0f;
#pragma unroll
            for (int t = 0; t < 9; ++t)
                s = fmaf(pw[t] * wk[t], xv[t + p * 3], s);
            ob[(size_t)j * HW + (size_t)(h + p) * WW + w] = s + pbias;
        }
    }
    if (half) {
        ob[(size_t)9 * HW + (size_t)h * WW + w] = 0.0f;
        ob[(size_t)9 * HW + (size_t)(h + 1) * WW + w] = 0.0f;
    }
}

// ---------------------------------------------------------------------------
extern "C" void kernel_launch(void* const* d_in, const int* in_sizes, int n_in,
                              void* d_out, int out_size, void* d_ws, size_t ws_size,
                              hipStream_t stream)
{
    const float* x    = (const float*)d_in[0];
    const float* w1   = (const float*)d_in[1];
    const float* w2   = (const float*)d_in[2];
    const float* w3   = (const float*)d_in[3];
    const float* pacw = (const float*)d_in[4];
    const float* pacb = (const float*)d_in[5];
    float* out = (float*)d_out;
    float* ws  = (float*)d_ws;

    float* wt1  = ws;            // 2880 floats
    float* wt2  = ws + 2880;     // 18432 floats
    float* wt3  = ws + 21312;    // 31104 floats
    float* bufs = ws + 52480;    // scratch for p1/p2

    transpose_weights<<<dim3((52416 + 255) / 256), dim3(256), 0, stream>>>(
        w1, w2, w3, wt1, wt2, wt3);

    const size_t need_full =
        ((size_t)52480 + (size_t)4 * 32 * HW + (size_t)4 * 64 * HW) * sizeof(float);
    dim3 blk(256);
    if (ws_size >= need_full) {
        float* p1 = bufs;                        // 4*32*HW
        float* p2 = p1 + (size_t)4 * 32 * HW;    // 4*64*HW
        conv2px_k<10, 10, 32, 32, true>
            <<<dim3(16, 8, 4), blk, 0, stream>>>(x, wt1, p1, 4);
        conv2px_k<32, 16, 64, 32, true>
            <<<dim3(16, 8, 8), blk, 0, stream>>>(p1, wt2, p2, 4);
        conv3_final2_k
            <<<dim3(16, 8, 8), blk, 0, stream>>>(p2, wt3, x, pacw, pacb, out, 4);
    } else {
        float* p1 = bufs;
        float* p2 = p1 + (size_t)32 * HW;
        for (int b = 0; b < 4; ++b) {
            const float* xb = x + (size_t)b * TB * HW;
            float* outb = out + (size_t)b * TB * HW;
            conv2px_k<10, 10, 32, 32, true>
                <<<dim3(16, 8, 1), blk, 0, stream>>>(xb, wt1, p1, 1);
            conv2px_k<32, 16, 64, 32, true>
                <<<dim3(16, 8, 2), blk, 0, stream>>>(p1, wt2, p2, 1);
            conv3_final2_k
                <<<dim3(16, 8, 2), blk, 0, stream>>>(p2, wt3, xb, pacw, pacb, outb, 1);
        }
    }
}

// Round 4
// 608.346 us; speedup vs baseline: 1.3215x; 1.3215x over previous
//
#include <hip/hip_runtime.h>
#include <math.h>

#define HH 256
#define WW 256
#define HW (HH * WW)
#define TB 10

__device__ __forceinline__ float sp10(float x) {
    float z = 10.0f * x;
    return (fmaxf(z, 0.0f) + log1pf(expf(-fabsf(z)))) * 0.1f;
}

// ---------------------------------------------------------------------------
// Weight transpose: OIHW -> [ci][tap][co] (co contiguous) for scalar-load use.
// wt3 picks only the 54 needed channels: [ci][tap][(tt-1)*6+g].
// ---------------------------------------------------------------------------
__global__ __launch_bounds__(256) void transpose_weights(
    const float* __restrict__ w1, const float* __restrict__ w2,
    const float* __restrict__ w3,
    float* __restrict__ wt1, float* __restrict__ wt2, float* __restrict__ wt3)
{
    int idx = blockIdx.x * 256 + threadIdx.x;
    if (idx < 2880) {               // conv1: (32,10,3,3) -> [ci<10][tap<9][co<32]
        int ci = idx / 288; int rem = idx - ci * 288;
        int tap = rem / 32; int co = rem - tap * 32;
        wt1[idx] = w1[co * 90 + ci * 9 + tap];
    }
    if (idx < 18432) {              // conv2: (64,32,3,3) -> [ci<32][tap<9][co<64]
        int ci = idx / 576; int rem = idx - ci * 576;
        int tap = rem / 64; int co = rem - tap * 64;
        wt2[idx] = w2[co * 288 + ci * 9 + tap];
    }
    if (idx < 31104) {              // conv3: (60,64,3,3) -> [ci<64][tap<9][54]
        int ci = idx / 486; int rem = idx - ci * 486;
        int tap = rem / 54; int j54 = rem - tap * 54;
        int tt = j54 / 6 + 1;
        int g  = j54 - (tt - 1) * 6;
        wt3[idx] = w3[(g * 10 + tt) * 576 + ci * 9 + tap];
    }
}

// NB must be a power of two so blockIdx.z decomposition stays in SGPRs
// (gfx950 has NO scalar divide; runtime '/' would poison wp into VGPRs ->
// per-lane vector weight loads -- the round-3 3x VALU blowup).
template <int NB> __device__ __forceinline__ int log2nb() {
    static_assert(NB == 1 || NB == 2 || NB == 4, "NB pow2");
    return NB == 4 ? 2 : (NB == 2 ? 1 : 0);
}

// ---------------------------------------------------------------------------
// 2-pixel-per-thread direct 3x3 conv. Block = 256 thr covers 16w x 32h tile
// (vertical pixel pairs). Output channels split via blockIdx.z halves so each
// scalar weight load feeds 2 FMAs. LDS: [CHUNK][34][18] floats.
// ---------------------------------------------------------------------------
template <int CIN, int CHUNK, int COUT, int CO_PER, int NB, bool RELU_IN>
__global__ __launch_bounds__(256, 4) void conv2px_k(
    const float* __restrict__ in, const float* __restrict__ wt,
    float* __restrict__ out)
{
    __shared__ float tile[CHUNK * 612];   // 34*18 = 612 per ci
    const int tx = threadIdx.x & 15, ty = threadIdx.x >> 4;
    const int h0 = blockIdx.y * 32, w0 = blockIdx.x * 16;
    const int z = blockIdx.z;
    const int bz = z & (NB - 1);
    const int half = z >> log2nb<NB>();
    const int base = half * CO_PER;
    const float* inb = in + (size_t)bz * CIN * HW;

    float acc0[CO_PER], acc1[CO_PER];
#pragma unroll
    for (int c = 0; c < CO_PER; ++c) { acc0[c] = 0.0f; acc1[c] = 0.0f; }

    for (int c0 = 0; c0 < CIN; c0 += CHUNK) {
        if (c0) __syncthreads();
        const float* inc = inb + (size_t)c0 * HW;
        for (int i = threadIdx.x; i < CHUNK * 612; i += 256) {
            int ci = i / 612; int r = i - ci * 612;
            int row = r / 18; int col = r - row * 18;
            int gy = h0 + row - 1, gx = w0 + col - 1;
            float v = 0.0f;
            if (gy >= 0 && gy < HH && gx >= 0 && gx < WW)
                v = inc[(size_t)ci * HW + gy * WW + gx];
            if (RELU_IN) v = fmaxf(v, 0.0f);
            tile[i] = v;
        }
        __syncthreads();

        for (int ci = 0; ci < CHUNK; ++ci) {
            const float* tp = &tile[ci * 612 + (2 * ty) * 18 + tx];
            float v[12];
#pragma unroll
            for (int r = 0; r < 4; ++r)
#pragma unroll
                for (int c = 0; c < 3; ++c)
                    v[r * 3 + c] = tp[r * 18 + c];
            const float* wp = wt + (size_t)(c0 + ci) * 9 * COUT + base;
#pragma unroll
            for (int t = 0; t < 9; ++t) {
                float a0 = v[t], a1 = v[t + 3];
#pragma unroll
                for (int c = 0; c < CO_PER; ++c) {
                    float wv = wp[t * COUT + c];
                    acc0[c] = fmaf(wv, a0, acc0[c]);
                    acc1[c] = fmaf(wv, a1, acc1[c]);
                }
            }
        }
    }

    const int h = h0 + 2 * ty, w = w0 + tx;
    float* ob = out + (size_t)bz * COUT * HW + (size_t)base * HW
                    + (size_t)h * WW + w;
#pragma unroll
    for (int c = 0; c < CO_PER; ++c) {
        ob[(size_t)c * HW]      = acc0[c];
        ob[(size_t)c * HW + WW] = acc1[c];
    }
}

// ---------------------------------------------------------------------------
// conv3 (64 -> 54 ch) + epilogue, 2px/thread, channel-halved:
// half 0: acc = global ch 0..29  -> epilogue j = 0..4
// half 1: acc = global ch 24..53 -> epilogue j = 4..8 (+ zero ch 9)
// j = 4 written bitwise-identically by both halves (same weights, same order).
// ---------------------------------------------------------------------------
template <int NB>
__global__ __launch_bounds__(256, 4) void conv3_final2_k(
    const float* __restrict__ p2, const float* __restrict__ wt3,
    const float* __restrict__ x, const float* __restrict__ pacw,
    const float* __restrict__ pacb, float* __restrict__ out)
{
    __shared__ float tile[16 * 612];
    const int tx = threadIdx.x & 15, ty = threadIdx.x >> 4;
    const int h0 = blockIdx.y * 32, w0 = blockIdx.x * 16;
    const int z = blockIdx.z;
    const int bz = z & (NB - 1);
    const int half = z >> log2nb<NB>();
    const int base = half * 24;
    const float* pbase = p2 + (size_t)bz * 64 * HW;

    float acc0[30], acc1[30];
#pragma unroll
    for (int c = 0; c < 30; ++c) { acc0[c] = 0.0f; acc1[c] = 0.0f; }

    for (int c0 = 0; c0 < 64; c0 += 16) {
        if (c0) __syncthreads();
        const float* inc = pbase + (size_t)c0 * HW;
        for (int i = threadIdx.x; i < 16 * 612; i += 256) {
            int ci = i / 612; int r = i - ci * 612;
            int row = r / 18; int col = r - row * 18;
            int gy = h0 + row - 1, gx = w0 + col - 1;
            float v = 0.0f;
            if (gy >= 0 && gy < HH && gx >= 0 && gx < WW)
                v = inc[(size_t)ci * HW + gy * WW + gx];
            tile[i] = v;
        }
        __syncthreads();

        for (int ci = 0; ci < 16; ++ci) {
            const float* tp = &tile[ci * 612 + (2 * ty) * 18 + tx];
            float v[12];
#pragma unroll
            for (int r = 0; r < 4; ++r)
#pragma unroll
                for (int c = 0; c < 3; ++c)
                    v[r * 3 + c] = tp[r * 18 + c];
            const float* wp = wt3 + (size_t)(c0 + ci) * 486 + base;
#pragma unroll
            for (int t = 0; t < 9; ++t) {
                float a0 = v[t], a1 = v[t + 3];
#pragma unroll
                for (int c = 0; c < 30; ++c) {
                    float wv = wp[t * 54 + c];
                    acc0[c] = fmaf(wv, a0, acc0[c]);
                    acc1[c] = fmaf(wv, a1, acc1[c]);
                }
            }
        }
    }

    // ---- epilogue ----
    float pw[9];
#pragma unroll
    for (int k = 0; k < 9; ++k) pw[k] = pacw[k];
    const float pbias = pacb[0];
    const int h = h0 + 2 * ty, w = w0 + tx;
    const float* xb = x + (size_t)bz * TB * HW;
    float* ob = out + (size_t)bz * TB * HW;

#pragma unroll
    for (int k = 0; k < 5; ++k) {
        const int j = half * 4 + k;
        const int tt = j + 1;
        const float* xc = xb + (size_t)tt * HW;
        float xv[12];
#pragma unroll
        for (int r = 0; r < 4; ++r)
#pragma unroll
            for (int c = 0; c < 3; ++c) {
                int gy = h + r - 1, gx = w + c - 1;
                xv[r * 3 + c] = (gy >= 0 && gy < HH && gx >= 0 && gx < WW)
                                    ? xc[gy * WW + gx] : 0.0f;
            }
#pragma unroll
        for (int p = 0; p < 2; ++p) {
            const float* ac = p ? acc1 : acc0;
            float kappa = sp10(ac[k * 6 + 0]);
            float m1d   = ac[k * 6 + 1];
            float m2d   = ac[k * 6 + 2];
            float gamma = sp10(ac[k * 6 + 3]);
            float vx    = ac[k * 6 + 4];
            float vy    = ac[k * 6 + 5];
            float H11 = gamma + vx * vx;
            float H22 = gamma + vy * vy;
            float H12 = vx * vy;
            float iH11 = 1.0f / H11;
            float iH22 = 1.0f / H22;
            float wk[9];
            wk[0] = -0.5f * H12;  wk[1] = -iH22 + m1d;  wk[2] = 0.5f * H12;
            wk[3] = -iH11 - m2d;
            wk[4] = kappa + 2.0f * H11 + 2.0f * H22 + 1.0f;
            wk[5] = -iH11 + m2d;
            wk[6] = 0.5f * H12;   wk[7] = -iH22 - m1d;  wk[8] = -0.5f * H12;
            float s = 0.0f;
#pragma unroll
            for (int t = 0; t < 9; ++t)
                s = fmaf(pw[t] * wk[t], xv[t + p * 3], s);
            ob[(size_t)j * HW + (size_t)(h + p) * WW + w] = s + pbias;
        }
    }
    if (half) {
        ob[(size_t)9 * HW + (size_t)h * WW + w] = 0.0f;
        ob[(size_t)9 * HW + (size_t)(h + 1) * WW + w] = 0.0f;
    }
}

// ---------------------------------------------------------------------------
extern "C" void kernel_launch(void* const* d_in, const int* in_sizes, int n_in,
                              void* d_out, int out_size, void* d_ws, size_t ws_size,
                              hipStream_t stream)
{
    const float* x    = (const float*)d_in[0];
    const float* w1   = (const float*)d_in[1];
    const float* w2   = (const float*)d_in[2];
    const float* w3   = (const float*)d_in[3];
    const float* pacw = (const float*)d_in[4];
    const float* pacb = (const float*)d_in[5];
    float* out = (float*)d_out;
    float* ws  = (float*)d_ws;

    float* wt1  = ws;            // 2880 floats
    float* wt2  = ws + 2880;     // 18432 floats
    float* wt3  = ws + 21312;    // 31104 floats
    float* bufs = ws + 52480;    // scratch for p1/p2

    transpose_weights<<<dim3((52416 + 255) / 256), dim3(256), 0, stream>>>(
        w1, w2, w3, wt1, wt2, wt3);

    const size_t need_full =
        ((size_t)52480 + (size_t)4 * 32 * HW + (size_t)4 * 64 * HW) * sizeof(float);
    dim3 blk(256);
    if (ws_size >= need_full) {
        float* p1 = bufs;                        // 4*32*HW
        float* p2 = p1 + (size_t)4 * 32 * HW;    // 4*64*HW
        conv2px_k<10, 10, 32, 32, 4, true>
            <<<dim3(16, 8, 4), blk, 0, stream>>>(x, wt1, p1);
        conv2px_k<32, 16, 64, 32, 4, true>
            <<<dim3(16, 8, 8), blk, 0, stream>>>(p1, wt2, p2);
        conv3_final2_k<4>
            <<<dim3(16, 8, 8), blk, 0, stream>>>(p2, wt3, x, pacw, pacb, out);
    } else {
        float* p1 = bufs;
        float* p2 = p1 + (size_t)32 * HW;
        for (int b = 0; b < 4; ++b) {
            const float* xb = x + (size_t)b * TB * HW;
            float* outb = out + (size_t)b * TB * HW;
            conv2px_k<10, 10, 32, 32, 1, true>
                <<<dim3(16, 8, 1), blk, 0, stream>>>(xb, wt1, p1);
            conv2px_k<32, 16, 64, 32, 1, true>
                <<<dim3(16, 8, 2), blk, 0, stream>>>(p1, wt2, p2);
            conv3_final2_k<1>
                <<<dim3(16, 8, 2), blk, 0, stream>>>(p2, wt3, xb, pacw, pacb, outb);
        }
    }
}

// Round 5
// 255.849 us; speedup vs baseline: 3.1423x; 2.3778x over previous
//
#include <hip/hip_runtime.h>
#include <math.h>

#define HH 256
#define WW 256
#define HW (HH * WW)
#define TB 10

typedef __attribute__((ext_vector_type(4))) float f32x4;
typedef __attribute__((ext_vector_type(8))) short s16x8;

__device__ __forceinline__ float sp10(float x) {
    float z = 10.0f * x;
    return (fmaxf(z, 0.0f) + log1pf(expf(-fabsf(z)))) * 0.1f;
}

// fp32 -> bf16 RNE
__device__ __forceinline__ unsigned short f2bf(float f) {
    unsigned u = __float_as_uint(f);
    u = u + 0x7FFFu + ((u >> 16) & 1u);
    return (unsigned short)(u >> 16);
}
// split v = hi + lo (both bf16); lo captures next 8 mantissa bits (~2^-17 rel)
__device__ __forceinline__ void bsplit(float v, unsigned short& h, unsigned short& l) {
    h = f2bf(v);
    float hf = __uint_as_float(((unsigned)h) << 16);
    l = f2bf(v - hf);
}
__device__ __forceinline__ unsigned pk(unsigned short a, unsigned short b) {
    return (unsigned)a | ((unsigned)b << 16);
}
// two floats -> packed bf16-hi pair + bf16-lo pair
__device__ __forceinline__ void sp2(float a, float b, unsigned& uh, unsigned& ul) {
    unsigned short h1, l1, h2, l2;
    bsplit(a, h1, l1); bsplit(b, h2, l2);
    uh = pk(h1, h2); ul = pk(l1, l2);
}

// ---------------------------------------------------------------------------
// Prep: conv1 weights -> [ci][tap][co32] fp32 (VALU path);
// conv2 -> [tap][co64][ci32] bf16 hi/lo; conv3 -> [tap][co64][ci64] hi/lo
// with 54-channel selection (co = (tt-1)*6+g), co 54..63 zero-padded.
// ---------------------------------------------------------------------------
__global__ __launch_bounds__(256) void prep_weights(
    const float* __restrict__ w1, const float* __restrict__ w2,
    const float* __restrict__ w3,
    float* __restrict__ wt1,
    unsigned short* __restrict__ wA2h, unsigned short* __restrict__ wA2l,
    unsigned short* __restrict__ wA3h, unsigned short* __restrict__ wA3l)
{
    int idx = blockIdx.x * 256 + threadIdx.x;
    if (idx < 2880) {                 // conv1: (32,10,3,3) -> [ci<10][tap<9][co<32]
        int ci = idx / 288; int rem = idx - ci * 288;
        int tap = rem / 32; int co = rem - tap * 32;
        wt1[idx] = w1[co * 90 + ci * 9 + tap];
    }
    if (idx < 18432) {                // conv2: (64,32,3,3) -> [t][co64][ci32]
        int t = idx / 2048; int rem = idx - t * 2048;
        int co = rem >> 5; int ci = rem & 31;
        unsigned short h, l;
        bsplit(w2[(co * 32 + ci) * 9 + t], h, l);
        wA2h[idx] = h; wA2l[idx] = l;
    }
    if (idx < 36864) {                // conv3: (60,64,3,3) -> [t][co64][ci64], 54 used
        int t = idx / 4096; int rem = idx - t * 4096;
        int co = rem >> 6; int ci = rem & 63;
        float v = 0.0f;
        if (co < 54) {
            int tt = co / 6 + 1;      // time 1..9
            int g  = co - (tt - 1) * 6;
            v = w3[((g * 10 + tt) * 64 + ci) * 9 + t];
        }
        unsigned short h, l;
        bsplit(v, h, l);
        wA3h[idx] = h; wA3l[idx] = l;
    }
}

// ---------------------------------------------------------------------------
// conv1 (10->32, VALU, 2px/thread, R4-verified structure). Writes
// q1 = relu(p1) as bf16 hi/lo planes in [b][h][w][ci32] layout for conv2 MFMA.
// ---------------------------------------------------------------------------
__global__ __launch_bounds__(256, 4) void conv1_k(
    const float* __restrict__ x, const float* __restrict__ wt1,
    unsigned short* __restrict__ q1h, unsigned short* __restrict__ q1l)
{
    __shared__ float tile[10 * 612];   // 34*18 per ci
    const int tx = threadIdx.x & 15, ty = threadIdx.x >> 4;
    const int h0 = blockIdx.y * 32, w0 = blockIdx.x * 16;
    const int b = blockIdx.z;
    const float* inb = x + (size_t)b * TB * HW;   // conv1 uses x[:, :10] = all t

    float acc0[32], acc1[32];
#pragma unroll
    for (int c = 0; c < 32; ++c) { acc0[c] = 0.0f; acc1[c] = 0.0f; }

    for (int i = threadIdx.x; i < 10 * 612; i += 256) {
        int ci = i / 612; int r = i - ci * 612;
        int row = r / 18; int col = r - row * 18;
        int gy = h0 + row - 1, gx = w0 + col - 1;
        float v = 0.0f;
        if (gy >= 0 && gy < HH && gx >= 0 && gx < WW)
            v = fmaxf(inb[(size_t)ci * HW + gy * WW + gx], 0.0f);  // relu(x)
        tile[i] = v;
    }
    __syncthreads();

    for (int ci = 0; ci < 10; ++ci) {
        const float* tp = &tile[ci * 612 + (2 * ty) * 18 + tx];
        float v[12];
#pragma unroll
        for (int r = 0; r < 4; ++r)
#pragma unroll
            for (int c = 0; c < 3; ++c)
                v[r * 3 + c] = tp[r * 18 + c];
        const float* wp = wt1 + ci * 288;
#pragma unroll
        for (int t = 0; t < 9; ++t) {
            float a0 = v[t], a1 = v[t + 3];
#pragma unroll
            for (int c = 0; c < 32; ++c) {
                float wv = wp[t * 32 + c];
                acc0[c] = fmaf(wv, a0, acc0[c]);
                acc1[c] = fmaf(wv, a1, acc1[c]);
            }
        }
    }

    const int h = h0 + 2 * ty, w = w0 + tx;
    const size_t q1base = (size_t)b * HW * 32;
#pragma unroll
    for (int p = 0; p < 2; ++p) {
        const float* src = p ? acc1 : acc0;
        size_t off = q1base + ((size_t)(h + p) * WW + w) * 32;
#pragma unroll
        for (int g = 0; g < 4; ++g) {
            uint4 Uh, Ul;
            sp2(fmaxf(src[g*8+0],0.f), fmaxf(src[g*8+1],0.f), Uh.x, Ul.x);  // relu(p1)
            sp2(fmaxf(src[g*8+2],0.f), fmaxf(src[g*8+3],0.f), Uh.y, Ul.y);
            sp2(fmaxf(src[g*8+4],0.f), fmaxf(src[g*8+5],0.f), Uh.z, Ul.z);
            sp2(fmaxf(src[g*8+6],0.f), fmaxf(src[g*8+7],0.f), Uh.w, Ul.w);
            *(uint4*)(q1h + off + g * 8) = Uh;
            *(uint4*)(q1l + off + g * 8) = Ul;
        }
    }
}

// ---------------------------------------------------------------------------
// conv2 (32->64) via mfma_f32_16x16x32_bf16, split-precision (3 products).
// Block = 16x16 px, 4 waves; wave owns 4 pixel-rows (n-tiles), all 4 co-tiles.
// k-chunk = one tap x 32 ci. LDS halo tile [18][18][hi32|lo32|pad8] shorts.
// Writes q2 = p2 RAW (no relu -- conv3 input is un-relu'd p!).
// ---------------------------------------------------------------------------
__global__ __launch_bounds__(256, 2) void conv2_mfma(
    const unsigned short* __restrict__ q1h, const unsigned short* __restrict__ q1l,
    const unsigned short* __restrict__ wA2h, const unsigned short* __restrict__ wA2l,
    unsigned short* __restrict__ q2h, unsigned short* __restrict__ q2l)
{
    __shared__ short lds[18 * 18 * 72];   // 46656 B
    const int tid = threadIdx.x;
    const int lane = tid & 63, wave = tid >> 6;
    const int px = lane & 15, quad = lane >> 4;
    const int h0 = blockIdx.y * 16, w0 = blockIdx.x * 16, b = blockIdx.z;

    // stage q1 hi+lo halo tile (plane-major for coalescing: 64B/lane chunks)
    for (int i = tid; i < 648; i += 256) {
        int plane = (i >= 324) ? 1 : 0;
        int rc = i - plane * 324;
        int row = rc / 18, col = rc - row * 18;
        int gy = h0 + row - 1, gx = w0 + col - 1;
        uint4 v0 = {0,0,0,0}, v1 = v0, v2 = v0, v3 = v0;
        if (gy >= 0 && gy < HH && gx >= 0 && gx < WW) {
            const uint4* gp = (const uint4*)((plane ? q1l : q1h)
                + (size_t)b * HW * 32 + ((size_t)gy * WW + gx) * 32);
            v0 = gp[0]; v1 = gp[1]; v2 = gp[2]; v3 = gp[3];
        }
        uint4* dp = (uint4*)&lds[(row * 18 + col) * 72 + plane * 32];
        dp[0] = v0; dp[1] = v1; dp[2] = v2; dp[3] = v3;
    }
    __syncthreads();

    f32x4 acc[4][4];
#pragma unroll
    for (int r = 0; r < 4; ++r)
#pragma unroll
        for (int ct = 0; ct < 4; ++ct)
            acc[r][ct] = (f32x4){0.f, 0.f, 0.f, 0.f};

#pragma unroll
    for (int t = 0; t < 9; ++t) {
        const int dy = t / 3, dx = t - 3 * (t / 3);
        s16x8 ah[4], al[4];
#pragma unroll
        for (int ct = 0; ct < 4; ++ct) {
            int wb = (t * 64 + ct * 16 + px) * 32 + quad * 8;  // A[m=px][k=quad*8+j]
            ah[ct] = *(const s16x8*)(wA2h + wb);
            al[ct] = *(const s16x8*)(wA2l + wb);
        }
#pragma unroll
        for (int r = 0; r < 4; ++r) {
            int py = wave * 4 + r;
            const short* bp = &lds[((py + dy) * 18 + (px + dx)) * 72 + quad * 8];
            s16x8 bh = *(const s16x8*)bp;        // B[k=quad*8+j][n=px]
            s16x8 bl = *(const s16x8*)(bp + 32);
#pragma unroll
            for (int ct = 0; ct < 4; ++ct) {
                acc[r][ct] = __builtin_amdgcn_mfma_f32_16x16x32_bf16(ah[ct], bh, acc[r][ct], 0, 0, 0);
                acc[r][ct] = __builtin_amdgcn_mfma_f32_16x16x32_bf16(ah[ct], bl, acc[r][ct], 0, 0, 0);
                acc[r][ct] = __builtin_amdgcn_mfma_f32_16x16x32_bf16(al[ct], bh, acc[r][ct], 0, 0, 0);
            }
        }
    }

    // store raw p2 as hi/lo: C row = co = ct*16 + quad*4 + reg, col = px
#pragma unroll
    for (int r = 0; r < 4; ++r) {
        int py = wave * 4 + r;
        size_t pix = (size_t)b * HW + (size_t)(h0 + py) * WW + (w0 + px);
#pragma unroll
        for (int ct = 0; ct < 4; ++ct) {
            int co0 = ct * 16 + quad * 4;
            uint2 Uh, Ul;
            sp2(acc[r][ct][0], acc[r][ct][1], Uh.x, Ul.x);
            sp2(acc[r][ct][2], acc[r][ct][3], Uh.y, Ul.y);
            size_t off = pix * 64 + co0;
            *(uint2*)(q2h + off) = Uh;
            *(uint2*)(q2l + off) = Ul;
        }
    }
}

// ---------------------------------------------------------------------------
// conv3 (64 -> 54, padded to 64) MFMA + params regroup through LDS + the
// R2-verified fp32 epilogue. CIN=64 staged as two 32-ci halves.
// ---------------------------------------------------------------------------
#define PSTR 260
__global__ __launch_bounds__(256, 2) void conv3_mfma(
    const unsigned short* __restrict__ q2h, const unsigned short* __restrict__ q2l,
    const unsigned short* __restrict__ wA3h, const unsigned short* __restrict__ wA3l,
    const float* __restrict__ x, const float* __restrict__ pacw,
    const float* __restrict__ pacb, float* __restrict__ out)
{
    __shared__ float smem[14080];    // 56320 B: staging (46656 B) / params (54*260*4 B)
    short* lds = (short*)smem;
    const int tid = threadIdx.x;
    const int lane = tid & 63, wave = tid >> 6;
    const int px = lane & 15, quad = lane >> 4;
    const int h0 = blockIdx.y * 16, w0 = blockIdx.x * 16, b = blockIdx.z;

    f32x4 acc[4][4];
#pragma unroll
    for (int r = 0; r < 4; ++r)
#pragma unroll
        for (int ct = 0; ct < 4; ++ct)
            acc[r][ct] = (f32x4){0.f, 0.f, 0.f, 0.f};

    for (int half = 0; half < 2; ++half) {
        __syncthreads();
        for (int i = tid; i < 648; i += 256) {
            int plane = (i >= 324) ? 1 : 0;
            int rc = i - plane * 324;
            int row = rc / 18, col = rc - row * 18;
            int gy = h0 + row - 1, gx = w0 + col - 1;
            uint4 v0 = {0,0,0,0}, v1 = v0, v2 = v0, v3 = v0;
            if (gy >= 0 && gy < HH && gx >= 0 && gx < WW) {
                const uint4* gp = (const uint4*)((plane ? q2l : q2h)
                    + (size_t)b * HW * 64 + ((size_t)gy * WW + gx) * 64 + half * 32);
                v0 = gp[0]; v1 = gp[1]; v2 = gp[2]; v3 = gp[3];
            }
            uint4* dp = (uint4*)&lds[(row * 18 + col) * 72 + plane * 32];
            dp[0] = v0; dp[1] = v1; dp[2] = v2; dp[3] = v3;
        }
        __syncthreads();

#pragma unroll
        for (int t = 0; t < 9; ++t) {
            const int dy = t / 3, dx = t - 3 * (t / 3);
            s16x8 ah[4], al[4];
#pragma unroll
            for (int ct = 0; ct < 4; ++ct) {
                int wb = (t * 64 + ct * 16 + px) * 64 + half * 32 + quad * 8;
                ah[ct] = *(const s16x8*)(wA3h + wb);
                al[ct] = *(const s16x8*)(wA3l + wb);
            }
#pragma unroll
            for (int r = 0; r < 4; ++r) {
                int py = wave * 4 + r;
                const short* bp = &lds[((py + dy) * 18 + (px + dx)) * 72 + quad * 8];
                s16x8 bh = *(const s16x8*)bp;
                s16x8 bl = *(const s16x8*)(bp + 32);
#pragma unroll
                for (int ct = 0; ct < 4; ++ct) {
                    acc[r][ct] = __builtin_amdgcn_mfma_f32_16x16x32_bf16(ah[ct], bh, acc[r][ct], 0, 0, 0);
                    acc[r][ct] = __builtin_amdgcn_mfma_f32_16x16x32_bf16(ah[ct], bl, acc[r][ct], 0, 0, 0);
                    acc[r][ct] = __builtin_amdgcn_mfma_f32_16x16x32_bf16(al[ct], bh, acc[r][ct], 0, 0, 0);
                }
            }
        }
    }

    // regroup params: [co][pxflat] fp32 in LDS
    __syncthreads();
    float* lds2 = smem;
#pragma unroll
    for (int r = 0; r < 4; ++r) {
        int pf = (wave * 4 + r) * 16 + px;
#pragma unroll
        for (int ct = 0; ct < 4; ++ct)
#pragma unroll
            for (int g = 0; g < 4; ++g) {
                int co = ct * 16 + quad * 4 + g;
                if (co < 54) lds2[co * PSTR + pf] = acc[r][ct][g];
            }
    }
    __syncthreads();

    // per-thread epilogue (R2-verified math, verbatim): thread = one pixel
    float ac[54];
#pragma unroll
    for (int c = 0; c < 54; ++c) ac[c] = lds2[c * PSTR + tid];

    float pw[9];
#pragma unroll
    for (int k = 0; k < 9; ++k) pw[k] = pacw[k];
    const float pbias = pacb[0];
    const int h = h0 + (tid >> 4), w = w0 + (tid & 15);
    const float* xb = x + (size_t)b * TB * HW;
    float* ob = out + (size_t)b * TB * HW;

#pragma unroll
    for (int j = 0; j < 9; ++j) {
        const int tt = j + 1;
        float kappa = sp10(ac[j * 6 + 0]);
        float m1d   = ac[j * 6 + 1];
        float m2d   = ac[j * 6 + 2];
        float gamma = sp10(ac[j * 6 + 3]);
        float vx    = ac[j * 6 + 4];
        float vy    = ac[j * 6 + 5];
        float H11 = gamma + vx * vx;
        float H22 = gamma + vy * vy;
        float H12 = vx * vy;
        float iH11 = 1.0f / H11;
        float iH22 = 1.0f / H22;
        float wk[9];
        wk[0] = -0.5f * H12;  wk[1] = -iH22 + m1d;  wk[2] = 0.5f * H12;
        wk[3] = -iH11 - m2d;
        wk[4] = kappa + 2.0f * H11 + 2.0f * H22 + 1.0f;
        wk[5] = -iH11 + m2d;
        wk[6] = 0.5f * H12;   wk[7] = -iH22 - m1d;  wk[8] = -0.5f * H12;

        const float* xc = xb + (size_t)tt * HW;
        float s = 0.0f;
#pragma unroll
        for (int dy = 0; dy < 3; ++dy)
#pragma unroll
            for (int dx = 0; dx < 3; ++dx) {
                int gy = h + dy - 1, gx = w + dx - 1;
                float xv = (gy >= 0 && gy < HH && gx >= 0 && gx < WW)
                               ? xc[gy * WW + gx] : 0.0f;
                s = fmaf(pw[dy * 3 + dx] * wk[dy * 3 + dx], xv, s);
            }
        ob[(size_t)j * HW + (size_t)h * WW + w] = s + pbias;
    }
    ob[(size_t)9 * HW + (size_t)h * WW + w] = 0.0f;
}

// ---------------------------------------------------------------------------
extern "C" void kernel_launch(void* const* d_in, const int* in_sizes, int n_in,
                              void* d_out, int out_size, void* d_ws, size_t ws_size,
                              hipStream_t stream)
{
    const float* x    = (const float*)d_in[0];
    const float* w1   = (const float*)d_in[1];
    const float* w2   = (const float*)d_in[2];
    const float* w3   = (const float*)d_in[3];
    const float* pacw = (const float*)d_in[4];
    const float* pacb = (const float*)d_in[5];
    float* out = (float*)d_out;
    char* p = (char*)d_ws;

    float* wt1 = (float*)p;                                       // 11520 B
    unsigned short* wA2h = (unsigned short*)(p + 11520);          // 36864 B
    unsigned short* wA2l = (unsigned short*)(p + 11520 + 36864);
    unsigned short* wA3h = (unsigned short*)(p + 11520 + 2 * 36864);          // 73728 B
    unsigned short* wA3l = (unsigned short*)(p + 11520 + 2 * 36864 + 73728);
    const size_t woff = 11520 + 2 * 36864 + 2 * 73728;            // 232704 B

    prep_weights<<<144, 256, 0, stream>>>(w1, w2, w3, wt1, wA2h, wA2l, wA3h, wA3l);

    const size_t q1sz1 = (size_t)HW * 32 * 2;   // one batch, one plane: 4 MB
    const size_t q2sz1 = (size_t)HW * 64 * 2;   // 8 MB
    const size_t need_full = woff + 4 * (2 * q1sz1 + 2 * q2sz1);  // ~101 MB
    dim3 blk(256);

    if (ws_size >= need_full) {
        unsigned short* q1h = (unsigned short*)(p + woff);
        unsigned short* q1l = (unsigned short*)(p + woff + 4 * q1sz1);
        unsigned short* q2h = (unsigned short*)(p + woff + 8 * q1sz1);
        unsigned short* q2l = (unsigned short*)(p + woff + 8 * q1sz1 + 4 * q2sz1);
        conv1_k<<<dim3(16, 8, 4), blk, 0, stream>>>(x, wt1, q1h, q1l);
        conv2_mfma<<<dim3(16, 16, 4), blk, 0, stream>>>(q1h, q1l, wA2h, wA2l, q2h, q2l);
        conv3_mfma<<<dim3(16, 16, 4), blk, 0, stream>>>(q2h, q2l, wA3h, wA3l,
                                                        x, pacw, pacb, out);
    } else {
        unsigned short* q1h = (unsigned short*)(p + woff);
        unsigned short* q1l = (unsigned short*)(p + woff + q1sz1);
        unsigned short* q2h = (unsigned short*)(p + woff + 2 * q1sz1);
        unsigned short* q2l = (unsigned short*)(p + woff + 2 * q1sz1 + q2sz1);
        for (int b = 0; b < 4; ++b) {
            const float* xb = x + (size_t)b * TB * HW;
            float* outb = out + (size_t)b * TB * HW;
            conv1_k<<<dim3(16, 8, 1), blk, 0, stream>>>(xb, wt1, q1h, q1l);
            conv2_mfma<<<dim3(16, 16, 1), blk, 0, stream>>>(q1h, q1l, wA2h, wA2l, q2h, q2l);
            conv3_mfma<<<dim3(16, 16, 1), blk, 0, stream>>>(q2h, q2l, wA3h, wA3l,
                                                            xb, pacw, pacb, outb);
        }
    }
}